// Round 3
// baseline (2450.238 us; speedup 1.0000x reference)
//
#include <hip/hip_runtime.h>
#include <hip/hip_bf16.h>
#include <stdint.h>

// Problem: LELayer_54022098649764 — f32 inputs (proven by NaN forensics R0-R2).
// x: [16384,512] f32, A: [512,512] f32; out: [16384,512] f32 =
//   sum over 10 nearest neighbors (euclidean, excl self, np-f32 semantics) of xW = x@A.
//
// No f32 MFMA on CDNA4 -> 2-way f16 split GEMM (hh+hl+lh, 3 MFMAs) gives
// f32-class precision at matrix-core rate. Ranking on d=sqrtf(d2), lowest-index
// tie-break, matching jax.lax.top_k(-d) stability.

typedef _Float16 f16x8 __attribute__((ext_vector_type(8)));
typedef float f32x4 __attribute__((ext_vector_type(4)));

#define NPTS 16384
#define DIM 512
#define KNN 10
#define TILE 128
#define BK 32
#define NPART 4
#define PARTC (NPTS / NPART)

// ws layout (bytes), total ~70.7 MB
#define OFF_SQ   0u
#define OFF_IDXH 65536u
#define OFF_DH   (OFF_IDXH + 2621440u)
#define OFF_IDX  (OFF_DH + 2621440u)
#define OFF_XH   (OFF_IDX + 655360u)
#define OFF_XL   (OFF_XH + 16777216u)
#define OFF_AHT  (OFF_XL + 16777216u)
#define OFF_ALT  (OFF_AHT + 524288u)
#define OFF_XW   (OFF_ALT + 524288u)

#define GLDS16(g, l) __builtin_amdgcn_global_load_lds( \
    (__attribute__((address_space(1))) const void*)(g), \
    (__attribute__((address_space(3))) void*)(l), 16, 0, 0)

// ---------------- k0: split x -> xh,xl (f16) and sq (f32) ----------------
__global__ __launch_bounds__(64) void split_x_kernel(const float* __restrict__ x,
                                                     _Float16* __restrict__ xh,
                                                     _Float16* __restrict__ xl,
                                                     float* __restrict__ sq) {
  const int row = blockIdx.x, tid = threadIdx.x;
  const float4* p = (const float4*)(x + (size_t)row * DIM);
  float4 a = p[tid * 2], b = p[tid * 2 + 1];
  float v[8] = {a.x, a.y, a.z, a.w, b.x, b.y, b.z, b.w};
  f16x8 h, l;
  float s = 0.f;
#pragma unroll
  for (int i = 0; i < 8; i++) {
    _Float16 hi = (_Float16)v[i];
    h[i] = hi;
    l[i] = (_Float16)(v[i] - (float)hi);
    s += v[i] * v[i];
  }
  *(f16x8*)(xh + (size_t)row * DIM + tid * 8) = h;
  *(f16x8*)(xl + (size_t)row * DIM + tid * 8) = l;
#pragma unroll
  for (int off = 32; off > 0; off >>= 1) s += __shfl_down(s, off);
  if (tid == 0) sq[row] = s;
}

// ---------------- k0b: split+transpose A -> AhT,AlT [n][k] f16 ----------------
__global__ __launch_bounds__(64) void split_at_kernel(const float* __restrict__ A,
                                                      _Float16* __restrict__ aht,
                                                      _Float16* __restrict__ alt) {
  const int n = blockIdx.x, tid = threadIdx.x;
#pragma unroll
  for (int i = 0; i < DIM / 64; i++) {
    const int k = i * 64 + tid;
    float v = A[(size_t)k * DIM + n];
    _Float16 h = (_Float16)v;
    aht[(size_t)n * DIM + k] = h;
    alt[(size_t)n * DIM + k] = (_Float16)(v - (float)h);
  }
}

// ---------------- k2: xW = x @ A via 3-MFMA f16 split, f32 out ----------------
__global__ __launch_bounds__(256) void xw_kernel(const _Float16* __restrict__ xh,
                                                 const _Float16* __restrict__ xl,
                                                 const _Float16* __restrict__ aht,
                                                 const _Float16* __restrict__ alt,
                                                 float* __restrict__ xw) {
  __shared__ __align__(16) _Float16 Ash[TILE * BK], Asl[TILE * BK];
  __shared__ __align__(16) _Float16 Bsh[TILE * BK], Bsl[TILE * BK];
  const int tid = threadIdx.x;
  const int nb = blockIdx.x & 3;
  const int rbk = blockIdx.x >> 2;
  const int r0 = rbk * TILE, n0 = nb * TILE;
  const int wv = tid >> 6, lane = tid & 63;
  const int wr = (wv & 1) * 64, wc = (wv >> 1) * 64;
  const int cl = lane & 15, quad = lane >> 4;
  const int strow = wv * 16 + (lane >> 2);
  const int stk = (lane & 3) * 8;

  f32x4 acc[4][4];
#pragma unroll
  for (int i = 0; i < 4; i++)
#pragma unroll
    for (int j = 0; j < 4; j++) acc[i][j] = (f32x4){0.f, 0.f, 0.f, 0.f};

  for (int kc = 0; kc < DIM / BK; kc++) {
    const int k0 = kc * BK;
#pragma unroll
    for (int q = 0; q < 2; q++) {
      const int row = q * 64 + strow;
      const int dst = q * 2048 + wv * 512 + lane * 8;
      GLDS16(xh + (size_t)(r0 + row) * DIM + k0 + stk, Ash + dst);
      GLDS16(xl + (size_t)(r0 + row) * DIM + k0 + stk, Asl + dst);
      GLDS16(aht + (size_t)(n0 + row) * DIM + k0 + stk, Bsh + dst);
      GLDS16(alt + (size_t)(n0 + row) * DIM + k0 + stk, Bsl + dst);
    }
    __syncthreads();
    f16x8 ah[4], al[4], bh[4], bl[4];
#pragma unroll
    for (int i = 0; i < 4; i++) {
      ah[i] = *(const f16x8*)(Ash + (wr + i * 16 + cl) * BK + quad * 8);
      al[i] = *(const f16x8*)(Asl + (wr + i * 16 + cl) * BK + quad * 8);
    }
#pragma unroll
    for (int j = 0; j < 4; j++) {
      bh[j] = *(const f16x8*)(Bsh + (wc + j * 16 + cl) * BK + quad * 8);
      bl[j] = *(const f16x8*)(Bsl + (wc + j * 16 + cl) * BK + quad * 8);
    }
#pragma unroll
    for (int i = 0; i < 4; i++)
#pragma unroll
      for (int j = 0; j < 4; j++) {
        acc[i][j] = __builtin_amdgcn_mfma_f32_16x16x32_f16(ah[i], bh[j], acc[i][j], 0, 0, 0);
        acc[i][j] = __builtin_amdgcn_mfma_f32_16x16x32_f16(ah[i], bl[j], acc[i][j], 0, 0, 0);
        acc[i][j] = __builtin_amdgcn_mfma_f32_16x16x32_f16(al[i], bh[j], acc[i][j], 0, 0, 0);
      }
    __syncthreads();
  }
#pragma unroll
  for (int i = 0; i < 4; i++)
#pragma unroll
    for (int r = 0; r < 4; r++) {
      const int row = r0 + wr + i * 16 + quad * 4 + r;
#pragma unroll
      for (int j = 0; j < 4; j++)
        xw[(size_t)row * DIM + n0 + wc + j * 16 + cl] = acc[i][j][r];
    }
}

// ---------------- k3: distances + top-10, per column quarter ----------------
__global__ __launch_bounds__(256) void knn_kernel(const _Float16* __restrict__ xh,
                                                  const _Float16* __restrict__ xl,
                                                  const float* __restrict__ sq,
                                                  int* __restrict__ idxh,
                                                  float* __restrict__ dh) {
  __shared__ __align__(16) _Float16 Ash[TILE * BK], Asl[TILE * BK];
  __shared__ __align__(16) _Float16 Bsh[TILE * BK], Bsl[TILE * BK];  // 32KB total; reused as d2buf
  __shared__ float listd[TILE][KNN];
  __shared__ int listi[TILE][KNN];
  __shared__ float sqA[TILE], sqB[TILE];

  const int tid = threadIdx.x;
  const int part = blockIdx.x >> 7;
  const int rb = blockIdx.x & 127;
  const int r0 = rb * TILE;
  const int cbase = part * PARTC;

  if (tid < TILE) {
    sqA[tid] = sq[r0 + tid];
#pragma unroll
    for (int q = 0; q < KNN; q++) { listd[tid][q] = INFINITY; listi[tid][q] = 0x7fffffff; }
  }
  float th = INFINITY, th2 = INFINITY;  // per-row (owner thread tid<128) in registers

  const int wv = tid >> 6, lane = tid & 63;
  const int wr = (wv & 1) * 64, wc = (wv >> 1) * 64;
  const int cl = lane & 15, quad = lane >> 4;
  const int strow = wv * 16 + (lane >> 2);
  const int stk = (lane & 3) * 8;

  float* d2buf = (float*)Ash;  // 128*34*4 = 17408 B, fits in the 32KB staging block

  f32x4 acc[4][4];

  for (int ct = 0; ct < PARTC / TILE; ct++) {
    const int c0 = cbase + ct * TILE;
    if (tid < TILE) sqB[tid] = sq[c0 + tid];
#pragma unroll
    for (int i = 0; i < 4; i++)
#pragma unroll
      for (int j = 0; j < 4; j++) acc[i][j] = (f32x4){0.f, 0.f, 0.f, 0.f};

    for (int kc = 0; kc < DIM / BK; kc++) {
      const int k0 = kc * BK;
#pragma unroll
      for (int q = 0; q < 2; q++) {
        const int row = q * 64 + strow;
        const int dst = q * 2048 + wv * 512 + lane * 8;
        GLDS16(xh + (size_t)(r0 + row) * DIM + k0 + stk, Ash + dst);
        GLDS16(xl + (size_t)(r0 + row) * DIM + k0 + stk, Asl + dst);
        GLDS16(xh + (size_t)(c0 + row) * DIM + k0 + stk, Bsh + dst);
        GLDS16(xl + (size_t)(c0 + row) * DIM + k0 + stk, Bsl + dst);
      }
      __syncthreads();
      f16x8 ah[4], al[4], bh[4], bl[4];
#pragma unroll
      for (int i = 0; i < 4; i++) {
        ah[i] = *(const f16x8*)(Ash + (wr + i * 16 + cl) * BK + quad * 8);
        al[i] = *(const f16x8*)(Asl + (wr + i * 16 + cl) * BK + quad * 8);
      }
#pragma unroll
      for (int j = 0; j < 4; j++) {
        bh[j] = *(const f16x8*)(Bsh + (wc + j * 16 + cl) * BK + quad * 8);
        bl[j] = *(const f16x8*)(Bsl + (wc + j * 16 + cl) * BK + quad * 8);
      }
#pragma unroll
      for (int i = 0; i < 4; i++)
#pragma unroll
        for (int j = 0; j < 4; j++) {
          acc[i][j] = __builtin_amdgcn_mfma_f32_16x16x32_f16(ah[i], bh[j], acc[i][j], 0, 0, 0);
          acc[i][j] = __builtin_amdgcn_mfma_f32_16x16x32_f16(ah[i], bl[j], acc[i][j], 0, 0, 0);
          acc[i][j] = __builtin_amdgcn_mfma_f32_16x16x32_f16(al[i], bh[j], acc[i][j], 0, 0, 0);
        }
      __syncthreads();
    }

    // 4 passes over 32-column strips: dump d2 (128x32, pad 34) + per-row serial scan.
#pragma unroll
    for (int p = 0; p < 4; p++) {
      const int j0 = (p & 1) * 2;  // j pair for this strip (within matching wc half)
      const bool mine = (p < 2) ? (wc == 0) : (wc == 64);
      if (mine) {
#pragma unroll
        for (int jj = 0; jj < 2; jj++) {
          const int j = j0 + jj;
          const float sb = sqB[wc + j * 16 + cl];
#pragma unroll
          for (int i = 0; i < 4; i++)
#pragma unroll
            for (int r = 0; r < 4; r++) {
              const int row = wr + i * 16 + quad * 4 + r;
              float d2 = fmaxf(sqA[row] + sb - 2.0f * acc[i][j][r], 0.0f);
              d2buf[row * 34 + jj * 16 + cl] = d2;
            }
        }
      }
      __syncthreads();
      if (tid < TILE) {
        const int rg = r0 + tid;
        const float* drow = d2buf + tid * 34;
        for (int c = 0; c < 32; c++) {
          const float d2 = drow[c];
          if (d2 > th2) continue;          // safe quick-reject (th2 slightly padded)
          const int cg = c0 + p * 32 + c;
          if (cg == rg) continue;
          const float d = sqrtf(d2);       // rank in d-domain like the reference
          float d9 = listd[tid][KNN - 1]; int j9 = listi[tid][KNN - 1];
          if (d < d9 || (d == d9 && cg < j9)) {
            int pp = KNN - 1;
            while (pp > 0) {
              float dp = listd[tid][pp - 1]; int ip = listi[tid][pp - 1];
              if (d < dp || (d == dp && cg < ip)) { listd[tid][pp] = dp; listi[tid][pp] = ip; pp--; }
              else break;
            }
            listd[tid][pp] = d; listi[tid][pp] = cg;
            th = listd[tid][KNN - 1];
            th2 = th * th * 1.000001f;     // upper bound so sqrt-domain ties aren't rejected
          }
        }
      }
      __syncthreads();
    }
  }

  if (tid < TILE) {
    const size_t base = ((size_t)part * NPTS + (r0 + tid)) * KNN;
#pragma unroll
    for (int q = 0; q < KNN; q++) { idxh[base + q] = listi[tid][q]; dh[base + q] = listd[tid][q]; }
  }
}

// ---------------- k4: 4-way merge of sorted (d, idx) lists ----------------
__global__ __launch_bounds__(256) void merge_kernel(const int* __restrict__ idxh,
                                                    const float* __restrict__ dh,
                                                    int* __restrict__ idx) {
  const int row = blockIdx.x * 256 + threadIdx.x;
  float d[NPART]; int ci[NPART]; int pos[NPART];
#pragma unroll
  for (int h = 0; h < NPART; h++) {
    pos[h] = 0;
    d[h] = dh[((size_t)h * NPTS + row) * KNN];
    ci[h] = idxh[((size_t)h * NPTS + row) * KNN];
  }
  int* o = idx + (size_t)row * KNN;
#pragma unroll
  for (int q = 0; q < KNN; q++) {
    int best = 0;
#pragma unroll
    for (int h = 1; h < NPART; h++)
      if (d[h] < d[best] || (d[h] == d[best] && ci[h] < ci[best])) best = h;
    o[q] = ci[best] & (NPTS - 1);  // mask: guarantees in-bounds downstream
    pos[best]++;
    if (pos[best] < KNN) {
      d[best] = dh[((size_t)best * NPTS + row) * KNN + pos[best]];
      ci[best] = idxh[((size_t)best * NPTS + row) * KNN + pos[best]];
    } else { d[best] = INFINITY; ci[best] = 0x7fffffff; }
  }
}

// ---------------- k5: gather-sum of 10 neighbor rows of xW (f32) ----------------
__global__ __launch_bounds__(128) void gather_kernel(const float* __restrict__ xw,
                                                     const int* __restrict__ idx,
                                                     float* __restrict__ out) {
  const int row = blockIdx.x, tid = threadIdx.x;
  const int* ip = idx + (size_t)row * KNN;
  float4 s = {0.f, 0.f, 0.f, 0.f};
#pragma unroll
  for (int j = 0; j < KNN; j++) {
    const int nb = ip[j] & (NPTS - 1);
    const float4 v = *(const float4*)(xw + (size_t)nb * DIM + tid * 4);
    s.x += v.x; s.y += v.y; s.z += v.z; s.w += v.w;
  }
  *(float4*)(out + (size_t)row * DIM + tid * 4) = s;
}

extern "C" void kernel_launch(void* const* d_in, const int* in_sizes, int n_in,
                              void* d_out, int out_size, void* d_ws, size_t ws_size,
                              hipStream_t stream) {
  const float* x = (const float*)d_in[0];
  const float* A = (const float*)d_in[1];
  float* out = (float*)d_out;
  char* ws = (char*)d_ws;
  float* sq = (float*)(ws + OFF_SQ);
  int* idxh = (int*)(ws + OFF_IDXH);
  float* dh = (float*)(ws + OFF_DH);
  int* idx = (int*)(ws + OFF_IDX);
  _Float16* xh = (_Float16*)(ws + OFF_XH);
  _Float16* xl = (_Float16*)(ws + OFF_XL);
  _Float16* aht = (_Float16*)(ws + OFF_AHT);
  _Float16* alt = (_Float16*)(ws + OFF_ALT);
  float* xw = (float*)(ws + OFF_XW);

  split_x_kernel<<<NPTS, 64, 0, stream>>>(x, xh, xl, sq);
  split_at_kernel<<<DIM, 64, 0, stream>>>(A, aht, alt);
  xw_kernel<<<(NPTS / TILE) * (DIM / TILE), 256, 0, stream>>>(xh, xl, aht, alt, xw);
  knn_kernel<<<NPART * (NPTS / TILE), 256, 0, stream>>>(xh, xl, sq, idxh, dh);
  merge_kernel<<<NPTS / 256, 256, 0, stream>>>(idxh, dh, idx);
  gather_kernel<<<NPTS, 128, 0, stream>>>(xw, idx, out);
}